// Round 1
// baseline (3823.817 us; speedup 1.0000x reference)
//
#include <hip/hip_runtime.h>
#include <math.h>

#define B_  32
#define T_  48
#define H_  1024
#define D_  512
#define V_  32000
#define G4  4096   // 4*H

// ---------------------------------------------------------------------------
// Tiled fp32 GEMM #1: x_gates.
//   out xg[r = t*B+b][n] = dot(embedding[tok(b,t)], W_ih[n]) + b_ih[n]+b_hh[n]
//   M=1536, N=4096, K=512. 128x128 tile, BK=16, 256 thr, 8x8 microtile (4+4).
// ---------------------------------------------------------------------------
__global__ __launch_bounds__(256)
void gemm_xg(const int* __restrict__ sent_inputs,
             const float* __restrict__ embedding,
             const float* __restrict__ W_ih,
             const float* __restrict__ b_ih,
             const float* __restrict__ b_hh,
             float* __restrict__ xg)
{
    __shared__ float As[16][132];   // K-major, pad 132 breaks bank aliasing
    __shared__ float Bs[16][132];
    __shared__ int   rowoff[128];   // embedding row offsets (elements)

    const int tid = threadIdx.x;
    const int rb  = blockIdx.x * 128;   // M tile base (12 tiles)
    const int nb  = blockIdx.y * 128;   // N tile base (32 tiles)

    if (tid < 128) {
        int r   = rb + tid;
        int t   = r >> 5;        // r = t*32 + b
        int b   = r & 31;
        int tok = sent_inputs[b * T_ + t];
        rowoff[tid] = tok * D_;
    }
    __syncthreads();

    const int ty = tid >> 4, tx = tid & 15;
    float acc[8][8];
#pragma unroll
    for (int i = 0; i < 8; ++i)
#pragma unroll
        for (int j = 0; j < 8; ++j) acc[i][j] = 0.f;

    for (int it = 0; it < D_ / 16; ++it) {
        const int k0 = it * 16;
        __syncthreads();
#pragma unroll
        for (int j = 0; j < 2; ++j) {
            int i  = tid + j * 256;        // 0..511
            int m  = i >> 2;               // 0..127
            int kk = (i & 3) << 2;         // 0,4,8,12
            float4 av = *reinterpret_cast<const float4*>(embedding + rowoff[m] + k0 + kk);
            As[kk+0][m] = av.x; As[kk+1][m] = av.y; As[kk+2][m] = av.z; As[kk+3][m] = av.w;
            float4 bv = *reinterpret_cast<const float4*>(W_ih + (size_t)(nb + m) * D_ + k0 + kk);
            Bs[kk+0][m] = bv.x; Bs[kk+1][m] = bv.y; Bs[kk+2][m] = bv.z; Bs[kk+3][m] = bv.w;
        }
        __syncthreads();
#pragma unroll
        for (int kk = 0; kk < 16; ++kk) {
            float4 a0 = *reinterpret_cast<const float4*>(&As[kk][ty * 4]);
            float4 a1 = *reinterpret_cast<const float4*>(&As[kk][64 + ty * 4]);
            float4 b0 = *reinterpret_cast<const float4*>(&Bs[kk][tx * 4]);
            float4 b1 = *reinterpret_cast<const float4*>(&Bs[kk][64 + tx * 4]);
            float a[8] = {a0.x,a0.y,a0.z,a0.w,a1.x,a1.y,a1.z,a1.w};
            float b[8] = {b0.x,b0.y,b0.z,b0.w,b1.x,b1.y,b1.z,b1.w};
#pragma unroll
            for (int i = 0; i < 8; ++i)
#pragma unroll
                for (int j = 0; j < 8; ++j) acc[i][j] = fmaf(a[i], b[j], acc[i][j]);
        }
    }

    float bias[8];
#pragma unroll
    for (int j = 0; j < 8; ++j) {
        int n = nb + ((j < 4) ? tx * 4 + j : 64 + tx * 4 + (j - 4));
        bias[j] = b_ih[n] + b_hh[n];
    }
#pragma unroll
    for (int i = 0; i < 8; ++i) {
        int m = (i < 4) ? ty * 4 + i : 64 + ty * 4 + (i - 4);
        int r = rb + m;
        float* op = xg + (size_t)r * G4 + nb;
        float4 v0 = make_float4(acc[i][0]+bias[0], acc[i][1]+bias[1],
                                acc[i][2]+bias[2], acc[i][3]+bias[3]);
        float4 v1 = make_float4(acc[i][4]+bias[4], acc[i][5]+bias[5],
                                acc[i][6]+bias[6], acc[i][7]+bias[7]);
        *reinterpret_cast<float4*>(op + tx * 4)      = v0;
        *reinterpret_cast<float4*>(op + 64 + tx * 4) = v1;
    }
}

// ---------------------------------------------------------------------------
// Tiled fp32 GEMM #2: logits.
//   out[r = b*T+t][v] = dot(hs[t][b][:], W_out[v]) + b_out[v]
//   M=1536, N=32000, K=1024. Writes directly into d_out in [B,T,V] layout.
// ---------------------------------------------------------------------------
__global__ __launch_bounds__(256)
void gemm_logits(const float* __restrict__ hs,
                 const float* __restrict__ W_out,
                 const float* __restrict__ b_out,
                 float* __restrict__ out)
{
    __shared__ float As[16][132];
    __shared__ float Bs[16][132];
    __shared__ int   rowoff[128];   // hs row offsets (elements)

    const int tid = threadIdx.x;
    const int rb  = blockIdx.x * 128;   // 12 tiles
    const int nb  = blockIdx.y * 128;   // 250 tiles

    if (tid < 128) {
        int r = rb + tid;
        int b = r / T_;            // r = b*48 + t
        int t = r - b * T_;
        rowoff[tid] = (t * B_ + b) * H_;
    }
    __syncthreads();

    const int ty = tid >> 4, tx = tid & 15;
    float acc[8][8];
#pragma unroll
    for (int i = 0; i < 8; ++i)
#pragma unroll
        for (int j = 0; j < 8; ++j) acc[i][j] = 0.f;

    for (int it = 0; it < H_ / 16; ++it) {
        const int k0 = it * 16;
        __syncthreads();
#pragma unroll
        for (int j = 0; j < 2; ++j) {
            int i  = tid + j * 256;
            int m  = i >> 2;
            int kk = (i & 3) << 2;
            float4 av = *reinterpret_cast<const float4*>(hs + rowoff[m] + k0 + kk);
            As[kk+0][m] = av.x; As[kk+1][m] = av.y; As[kk+2][m] = av.z; As[kk+3][m] = av.w;
            float4 bv = *reinterpret_cast<const float4*>(W_out + (size_t)(nb + m) * H_ + k0 + kk);
            Bs[kk+0][m] = bv.x; Bs[kk+1][m] = bv.y; Bs[kk+2][m] = bv.z; Bs[kk+3][m] = bv.w;
        }
        __syncthreads();
#pragma unroll
        for (int kk = 0; kk < 16; ++kk) {
            float4 a0 = *reinterpret_cast<const float4*>(&As[kk][ty * 4]);
            float4 a1 = *reinterpret_cast<const float4*>(&As[kk][64 + ty * 4]);
            float4 b0 = *reinterpret_cast<const float4*>(&Bs[kk][tx * 4]);
            float4 b1 = *reinterpret_cast<const float4*>(&Bs[kk][64 + tx * 4]);
            float a[8] = {a0.x,a0.y,a0.z,a0.w,a1.x,a1.y,a1.z,a1.w};
            float b[8] = {b0.x,b0.y,b0.z,b0.w,b1.x,b1.y,b1.z,b1.w};
#pragma unroll
            for (int i = 0; i < 8; ++i)
#pragma unroll
                for (int j = 0; j < 8; ++j) acc[i][j] = fmaf(a[i], b[j], acc[i][j]);
        }
    }

    float bias[8];
#pragma unroll
    for (int j = 0; j < 8; ++j) {
        int n = nb + ((j < 4) ? tx * 4 + j : 64 + tx * 4 + (j - 4));
        bias[j] = b_out[n];
    }
#pragma unroll
    for (int i = 0; i < 8; ++i) {
        int m = (i < 4) ? ty * 4 + i : 64 + ty * 4 + (i - 4);
        int r = rb + m;
        float* op = out + (size_t)r * V_ + nb;
        float4 v0 = make_float4(acc[i][0]+bias[0], acc[i][1]+bias[1],
                                acc[i][2]+bias[2], acc[i][3]+bias[3]);
        float4 v1 = make_float4(acc[i][4]+bias[4], acc[i][5]+bias[5],
                                acc[i][6]+bias[6], acc[i][7]+bias[7]);
        *reinterpret_cast<float4*>(op + tx * 4)      = v0;
        *reinterpret_cast<float4*>(op + 64 + tx * 4) = v1;
    }
}

// ---------------------------------------------------------------------------
// hx0 = hidden_state[b, sent_len[b]-1, :]; cx = 0
// ---------------------------------------------------------------------------
__global__ __launch_bounds__(256)
void lstm_init(const float* __restrict__ hidden_state,
               const int* __restrict__ sent_len,
               float* __restrict__ hx0, float* __restrict__ cx)
{
    int idx = blockIdx.x * 256 + threadIdx.x;    // 32768 total
    int b = idx >> 10, h = idx & 1023;
    int sl = sent_len[b];
    hx0[idx] = hidden_state[((size_t)b * T_ + (sl - 1)) * H_ + h];
    cx[idx] = 0.f;
}

// ---------------------------------------------------------------------------
// One LSTM step. 256 blocks; block = 4 h-indices x 4 gates x 32 batches.
// gates[b][g*H+h] = dot(hx_in[b], W_hh[g*H+h]) + xg_t[b][g*H+h]; fused update.
// Each W_hh row is read by exactly one block (16.8 MB/step from L2/L3).
// hx ping-pongs across steps (cross-block WAR); cx is same-thread in-place.
// ---------------------------------------------------------------------------
__global__ __launch_bounds__(256)
void lstm_step(const float* __restrict__ W_hh,
               const float* __restrict__ xg_t,   // [B][4096] for this t
               const float* __restrict__ hx_in,  // [B][H]
               float* __restrict__ hx_out,       // [B][H]
               float* __restrict__ cx,           // [B][H]
               float* __restrict__ hs_t)         // [B][H] slice of hs[t]
{
    __shared__ float g_s[32][16];
    const int tid  = threadIdx.x;
    const int nl   = tid & 15;        // gate*4 + hl
    const int gate = nl >> 2;
    const int hl   = nl & 3;
    const int bq   = tid >> 4;        // 0..15 -> batches bq and bq+16
    const int h0   = blockIdx.x * 4;  // 256 blocks cover H=1024
    const int h    = h0 + hl;
    const int wrow = gate * H_ + h;

    const float4* W4  = reinterpret_cast<const float4*>(W_hh + (size_t)wrow * H_);
    const float4* ha4 = reinterpret_cast<const float4*>(hx_in + bq * H_);
    const float4* hb4 = reinterpret_cast<const float4*>(hx_in + (bq + 16) * H_);

    // 8 independent FMA chains to stay latency-hidden
    float4 s0 = make_float4(0.f,0.f,0.f,0.f);
    float4 s1 = make_float4(0.f,0.f,0.f,0.f);
#pragma unroll 4
    for (int k = 0; k < H_ / 4; ++k) {
        float4 w = W4[k];
        float4 a = ha4[k];
        float4 b = hb4[k];
        s0.x = fmaf(w.x, a.x, s0.x); s0.y = fmaf(w.y, a.y, s0.y);
        s0.z = fmaf(w.z, a.z, s0.z); s0.w = fmaf(w.w, a.w, s0.w);
        s1.x = fmaf(w.x, b.x, s1.x); s1.y = fmaf(w.y, b.y, s1.y);
        s1.z = fmaf(w.z, b.z, s1.z); s1.w = fmaf(w.w, b.w, s1.w);
    }
    float acc0 = (s0.x + s0.y) + (s0.z + s0.w);
    float acc1 = (s1.x + s1.y) + (s1.z + s1.w);
    acc0 += xg_t[bq * G4 + wrow];
    acc1 += xg_t[(bq + 16) * G4 + wrow];

    g_s[bq][nl]      = acc0;
    g_s[bq + 16][nl] = acc1;
    __syncthreads();

    if (tid < 128) {            // 32 b x 4 h pointwise updates
        int b   = tid >> 2;
        int hl2 = tid & 3;
        float iv = g_s[b][0 + hl2];
        float fv = g_s[b][4 + hl2];
        float gv = g_s[b][8 + hl2];
        float ov = g_s[b][12 + hl2];
        float is = 1.f / (1.f + expf(-iv));
        float fs = 1.f / (1.f + expf(-fv));
        float gt = tanhf(gv);
        float os = 1.f / (1.f + expf(-ov));
        int hh = h0 + hl2;
        float c  = fs * cx[b * H_ + hh] + is * gt;
        float hn = os * tanhf(c);
        cx[b * H_ + hh]     = c;
        hx_out[b * H_ + hh] = hn;
        hs_t[b * H_ + hh]   = hn;
    }
}

// ---------------------------------------------------------------------------
// Row-wise argmax over V=32000; lowest index wins ties (numpy semantics).
// predicts output layout is [B][T] = same row order r = b*T+t as logits rows.
// ---------------------------------------------------------------------------
__global__ __launch_bounds__(256)
void argmax_k(const float* __restrict__ logits, float* __restrict__ outi)
{
    __shared__ float sv[256];
    __shared__ int   si[256];
    int r = blockIdx.x;
    const float* row = logits + (size_t)r * V_;
    float best = -INFINITY;
    int   bi   = 0;
    for (int v = threadIdx.x; v < V_; v += 256) {   // indices ascend per thread
        float x = row[v];
        if (x > best) { best = x; bi = v; }
    }
    sv[threadIdx.x] = best; si[threadIdx.x] = bi;
    __syncthreads();
    for (int s = 128; s > 0; s >>= 1) {
        if (threadIdx.x < s) {
            float ov = sv[threadIdx.x + s]; int oi = si[threadIdx.x + s];
            if (ov > sv[threadIdx.x] ||
                (ov == sv[threadIdx.x] && oi < si[threadIdx.x])) {
                sv[threadIdx.x] = ov; si[threadIdx.x] = oi;
            }
        }
        __syncthreads();
    }
    if (threadIdx.x == 0) outi[r] = (float)si[0];
}

// ---------------------------------------------------------------------------
extern "C" void kernel_launch(void* const* d_in, const int* in_sizes, int n_in,
                              void* d_out, int out_size, void* d_ws, size_t ws_size,
                              hipStream_t stream)
{
    const int*   sent_inputs  = (const int*)  d_in[0];
    const float* hidden_state = (const float*)d_in[1];
    const int*   sent_len     = (const int*)  d_in[2];
    // d_in[3] = teacher_forcing_ratio (always 1, teacher forcing hard-coded)
    const float* embedding    = (const float*)d_in[4];
    const float* W_ih         = (const float*)d_in[5];
    const float* W_hh         = (const float*)d_in[6];
    const float* b_ih         = (const float*)d_in[7];
    const float* b_hh         = (const float*)d_in[8];
    const float* W_out        = (const float*)d_in[9];
    const float* b_out        = (const float*)d_in[10];
    float* out = (float*)d_out;

    // workspace layout (floats): xg | hs | hx0 | hx1 | cx   (~31.9 MB)
    float* ws  = (float*)d_ws;
    float* xg  = ws;                               // T*B*4096
    float* hs  = xg  + (size_t)T_ * B_ * G4;       // T*B*H
    float* hx0 = hs  + (size_t)T_ * B_ * H_;       // B*H
    float* hx1 = hx0 + B_ * H_;                    // B*H
    float* cx  = hx1 + B_ * H_;                    // B*H

    dim3 blk(256);
    gemm_xg<<<dim3(12, 32), blk, 0, stream>>>(sent_inputs, embedding, W_ih, b_ih, b_hh, xg);
    lstm_init<<<dim3(128), blk, 0, stream>>>(hidden_state, sent_len, hx0, cx);
    for (int t = 0; t < T_; ++t) {
        const float* hin = (t & 1) ? hx1 : hx0;
        float*      hout = (t & 1) ? hx0 : hx1;
        lstm_step<<<dim3(256), blk, 0, stream>>>(W_hh, xg + (size_t)t * B_ * G4,
                                                 hin, hout, cx, hs + (size_t)t * B_ * H_);
    }
    gemm_logits<<<dim3(12, 250), blk, 0, stream>>>(hs, W_out, b_out, out);
    argmax_k<<<dim3(B_ * T_), blk, 0, stream>>>(out, out + (size_t)B_ * T_ * V_);
}